// Round 1
// baseline (116.556 us; speedup 1.0000x reference)
//
#include <hip/hip_runtime.h>
#include <cstddef>

#define B_    8
#define T_EN_ 512
#define T_DE_ 128
#define D_    512
#define U_    256

// tanh(x) = 1 - 2/(exp2(C*x)+1), C = 2*log2(e)
#define TANH_C 2.8853900817779268f
#define L2E_   1.4426950408889634f

// ---------------------------------------------------------------------------
// Kernel 1: Y[M,U] = X[M,D] @ W[D,U]  (f32 vector GEMM, 64x64 tile, 4x4/thread)
// grid = (M/64, U/64), block = 256
// ---------------------------------------------------------------------------
__global__ __launch_bounds__(256) void proj_gemm_kernel(
    const float* __restrict__ X, const float* __restrict__ W,
    float* __restrict__ Y) {
  __shared__ float Xs[16][68];   // [k][row], +4 pad keeps b128 reads 16B-aligned, writes <=2-way
  __shared__ float Ws[16][64];   // [k][col]

  const int tid = threadIdx.x;
  const int tx  = tid & 15;      // col group (x4)
  const int ty  = tid >> 4;      // row group (x4)
  const int rowBase = blockIdx.x * 64;
  const int colBase = blockIdx.y * 64;

  // loader mapping: X tile 64x16 (one float4 per thread), W tile 16x64
  const int lr = tid >> 2;       // X row 0..63
  const int lq = tid & 3;        // X k-quad 0..3
  const int wk = tid >> 4;       // W k 0..15
  const int wn = tid & 15;       // W n-quad 0..15

  float acc[4][4] = {};

  for (int k0 = 0; k0 < D_; k0 += 16) {
    const float4 xv4 = *(const float4*)(X + (size_t)(rowBase + lr) * D_ + k0 + lq * 4);
    const float4 wv4 = *(const float4*)(W + (size_t)(k0 + wk) * U_ + colBase + wn * 4);
    Xs[lq * 4 + 0][lr] = xv4.x;
    Xs[lq * 4 + 1][lr] = xv4.y;
    Xs[lq * 4 + 2][lr] = xv4.z;
    Xs[lq * 4 + 3][lr] = xv4.w;
    *(float4*)&Ws[wk][wn * 4] = wv4;
    __syncthreads();

    #pragma unroll
    for (int k = 0; k < 16; ++k) {
      const float4 a4 = *(const float4*)&Xs[k][ty * 4];
      const float4 b4 = *(const float4*)&Ws[k][tx * 4];
      const float av[4] = {a4.x, a4.y, a4.z, a4.w};
      const float bv[4] = {b4.x, b4.y, b4.z, b4.w};
      #pragma unroll
      for (int m = 0; m < 4; ++m)
        #pragma unroll
        for (int n = 0; n < 4; ++n)
          acc[m][n] = fmaf(av[m], bv[n], acc[m][n]);
    }
    __syncthreads();
  }

  #pragma unroll
  for (int m = 0; m < 4; ++m) {
    const float4 o = make_float4(acc[m][0], acc[m][1], acc[m][2], acc[m][3]);
    *(float4*)(Y + (size_t)(rowBase + ty * 4 + m) * U_ + colBase + tx * 4) = o;
  }
}

// ---------------------------------------------------------------------------
// Kernel 2: mu[b,j,i] = sum_u tanh(att_de[b,j,u] + att_en[b,i,u]) * nu[u]
//           out[b,j,:] = softmax(mu[b,j,:] + (mask-1)*1e6)
// grid = B * T_DE/2 blocks, 512 threads (8 waves).
// wave w: j = j0 + (w>>2), i in [ (w&3)*128, (w&3)*128+128 ).
// lane l covers u = 4l..4l+3.
// ---------------------------------------------------------------------------
__global__ __launch_bounds__(512) void attn_main_kernel(
    const float* __restrict__ att_en, const float* __restrict__ att_de,
    const float* __restrict__ nu, const int* __restrict__ mask,
    float* __restrict__ out) {
  __shared__ float mu_s[2][T_EN_];

  const int tid  = threadIdx.x;
  const int lane = tid & 63;
  const int w    = tid >> 6;          // 0..7
  const int b    = blockIdx.x >> 6;   // / (T_DE/2)
  const int j0   = (blockIdx.x & 63) * 2;
  const int jl   = w >> 2;            // 0..1
  const int seg  = w & 3;             // 0..3
  const int j    = j0 + jl;

  const float4 de4 = *(const float4*)(att_de + (size_t)(b * T_DE_ + j) * U_ + lane * 4);
  const float4 nu4 = *(const float4*)(nu + lane * 4);
  const float dc0 = de4.x * TANH_C;
  const float dc1 = de4.y * TANH_C;
  const float dc2 = de4.z * TANH_C;
  const float dc3 = de4.w * TANH_C;

  const float* enb = att_en + (size_t)b * T_EN_ * U_ + lane * 4;

  const int i0 = seg * 128, i1 = i0 + 128;
  float4 nxt = *(const float4*)(enb + (size_t)i0 * U_);
  for (int i = i0; i < i1; ++i) {
    const float4 cur = nxt;
    const int inx = (i + 1 < i1) ? (i + 1) : i;
    nxt = *(const float4*)(enb + (size_t)inx * U_);

    const float z0 = fmaf(cur.x, TANH_C, dc0);
    const float z1 = fmaf(cur.y, TANH_C, dc1);
    const float z2 = fmaf(cur.z, TANH_C, dc2);
    const float z3 = fmaf(cur.w, TANH_C, dc3);
    const float e0 = __builtin_amdgcn_exp2f(z0);
    const float e1 = __builtin_amdgcn_exp2f(z1);
    const float e2 = __builtin_amdgcn_exp2f(z2);
    const float e3 = __builtin_amdgcn_exp2f(z3);
    const float r0 = __builtin_amdgcn_rcpf(e0 + 1.0f);
    const float r1 = __builtin_amdgcn_rcpf(e1 + 1.0f);
    const float r2 = __builtin_amdgcn_rcpf(e2 + 1.0f);
    const float r3 = __builtin_amdgcn_rcpf(e3 + 1.0f);
    const float t0 = fmaf(-2.0f, r0, 1.0f);
    const float t1 = fmaf(-2.0f, r1, 1.0f);
    const float t2 = fmaf(-2.0f, r2, 1.0f);
    const float t3 = fmaf(-2.0f, r3, 1.0f);
    float s = fmaf(t0, nu4.x, fmaf(t1, nu4.y, fmaf(t2, nu4.z, t3 * nu4.w)));

    #pragma unroll
    for (int off = 32; off; off >>= 1) s += __shfl_xor(s, off, 64);
    if (lane == 0) mu_s[jl][i] = s;
  }

  __syncthreads();

  // Softmax: wave 0 -> j0, wave 1 -> j0+1
  if (w < 2) {
    const int jj = j0 + w;
    float vals[8];
    float mx = -3.0e38f;
    #pragma unroll
    for (int k = 0; k < 8; ++k) {
      const int i = lane + 64 * k;
      const float mi = (float)mask[b * T_EN_ + i];
      const float v = fmaf(mi - 1.0f, 1.0e6f, mu_s[w][i]);
      vals[k] = v;
      mx = fmaxf(mx, v);
    }
    #pragma unroll
    for (int off = 32; off; off >>= 1) mx = fmaxf(mx, __shfl_xor(mx, off, 64));
    float sum = 0.0f;
    #pragma unroll
    for (int k = 0; k < 8; ++k) {
      const float e = __builtin_amdgcn_exp2f((vals[k] - mx) * L2E_);
      vals[k] = e;
      sum += e;
    }
    #pragma unroll
    for (int off = 32; off; off >>= 1) sum += __shfl_xor(sum, off, 64);
    const float inv = __builtin_amdgcn_rcpf(sum);
    float* op = out + (size_t)(b * T_DE_ + jj) * T_EN_;
    #pragma unroll
    for (int k = 0; k < 8; ++k) op[lane + 64 * k] = vals[k] * inv;
  }
}

// ---------------------------------------------------------------------------
extern "C" void kernel_launch(void* const* d_in, const int* in_sizes, int n_in,
                              void* d_out, int out_size, void* d_ws, size_t ws_size,
                              hipStream_t stream) {
  const float* en   = (const float*)d_in[0];   // [B, T_EN, D]
  const float* de   = (const float*)d_in[1];   // [B, T_DE, D]
  const int*   mask = (const int*)d_in[2];     // [B, T_EN]
  const float* w_en = (const float*)d_in[3];   // [D, U]
  const float* w_de = (const float*)d_in[4];   // [D, U]
  const float* nu   = (const float*)d_in[5];   // [U, 1]
  float* out = (float*)d_out;                  // [B, T_DE, T_EN]

  float* att_en = (float*)d_ws;                            // B*T_EN*U floats = 4 MB
  float* att_de = att_en + (size_t)B_ * T_EN_ * U_;        // B*T_DE*U floats = 1 MB

  // Projections
  proj_gemm_kernel<<<dim3((B_ * T_EN_) / 64, U_ / 64), 256, 0, stream>>>(en, w_en, att_en);
  proj_gemm_kernel<<<dim3((B_ * T_DE_) / 64, U_ / 64), 256, 0, stream>>>(de, w_de, att_de);

  // tanh-attention + masked softmax
  attn_main_kernel<<<dim3(B_ * (T_DE_ / 2)), 512, 0, stream>>>(att_en, att_de, nu, mask, out);
}

// Round 2
// 62.654 us; speedup vs baseline: 1.8603x; 1.8603x over previous
//
#include <hip/hip_runtime.h>
#include <cstddef>

#define B_    8
#define T_EN_ 512
#define T_DE_ 128
#define D_    512
#define U_    256

// tanh(x) = 1 - 2/(exp2(C*x)+1), C = 2*log2(e)
#define TANH_C 2.8853900817779268f
#define L2E_   1.4426950408889634f
#define TANH_CLAMP 0.99999994f

// ---------------------------------------------------------------------------
// Kernel 1: fused projections + tanh epilogue.
//   en_t = tanh(en @ w_en)   (4096 x 256)
//   de_t = tanh(de @ w_de)   (1024 x 256)
// Tile 32 rows x 32 cols, K-step 32, 128 threads (2 waves).
// grid = (160, 8): row-tiles 0..127 -> en, 128..159 -> de. 1280 blocks, 5/CU.
// ---------------------------------------------------------------------------
__global__ __launch_bounds__(128) void proj_tanh_kernel(
    const float* __restrict__ en, const float* __restrict__ de,
    const float* __restrict__ w_en, const float* __restrict__ w_de,
    float* __restrict__ en_t, float* __restrict__ de_t) {
  __shared__ float Xs[32][34];   // [k][row], pitch 34 -> conflict-free b64 reads
  __shared__ float Ws[32][32];   // [k][col]

  const int tid = threadIdx.x;
  const int rt = blockIdx.x;
  const int colBase = blockIdx.y * 32;

  const float *X, *W;
  float* Y;
  int rowBase;
  if (rt < 128) { X = en; W = w_en; Y = en_t; rowBase = rt * 32; }
  else          { X = de; W = w_de; Y = de_t; rowBase = (rt - 128) * 32; }

  const int xr = tid >> 2;      // X row 0..31
  const int xq = tid & 3;       // X k-quad (also xq+4)
  const int wk = tid >> 3;      // W k 0..15 (also +16)
  const int wc = tid & 7;       // W col-quad
  const int tx = tid & 7;       // compute col-quad
  const int ty = tid >> 3;      // compute row-pair 0..15

  float acc[2][4] = {};

  for (int k0 = 0; k0 < D_; k0 += 32) {
    const float4 xv0 = *(const float4*)(X + (size_t)(rowBase + xr) * D_ + k0 + xq * 4);
    const float4 xv1 = *(const float4*)(X + (size_t)(rowBase + xr) * D_ + k0 + (xq + 4) * 4);
    const float4 wv0 = *(const float4*)(W + (size_t)(k0 + wk) * U_ + colBase + wc * 4);
    const float4 wv1 = *(const float4*)(W + (size_t)(k0 + wk + 16) * U_ + colBase + wc * 4);
    __syncthreads();
    Xs[xq * 4 + 0][xr] = xv0.x;
    Xs[xq * 4 + 1][xr] = xv0.y;
    Xs[xq * 4 + 2][xr] = xv0.z;
    Xs[xq * 4 + 3][xr] = xv0.w;
    Xs[xq * 4 + 16][xr] = xv1.x;
    Xs[xq * 4 + 17][xr] = xv1.y;
    Xs[xq * 4 + 18][xr] = xv1.z;
    Xs[xq * 4 + 19][xr] = xv1.w;
    *(float4*)&Ws[wk][wc * 4] = wv0;
    *(float4*)&Ws[wk + 16][wc * 4] = wv1;
    __syncthreads();

    #pragma unroll
    for (int k = 0; k < 32; ++k) {
      const float2 a = *(const float2*)&Xs[k][ty * 2];
      const float4 bv = *(const float4*)&Ws[k][tx * 4];
      acc[0][0] = fmaf(a.x, bv.x, acc[0][0]);
      acc[0][1] = fmaf(a.x, bv.y, acc[0][1]);
      acc[0][2] = fmaf(a.x, bv.z, acc[0][2]);
      acc[0][3] = fmaf(a.x, bv.w, acc[0][3]);
      acc[1][0] = fmaf(a.y, bv.x, acc[1][0]);
      acc[1][1] = fmaf(a.y, bv.y, acc[1][1]);
      acc[1][2] = fmaf(a.y, bv.z, acc[1][2]);
      acc[1][3] = fmaf(a.y, bv.w, acc[1][3]);
    }
  }

  // tanh epilogue (clamped away from exactly +-1 so 1 + A*E > 0 downstream)
  #pragma unroll
  for (int r = 0; r < 2; ++r) {
    float4 o;
    float* oo = (float*)&o;
    #pragma unroll
    for (int c = 0; c < 4; ++c) {
      const float e = __builtin_amdgcn_exp2f(acc[r][c] * TANH_C);
      float t = fmaf(-2.0f, __builtin_amdgcn_rcpf(e + 1.0f), 1.0f);
      t = fminf(fmaxf(t, -TANH_CLAMP), TANH_CLAMP);
      oo[c] = t;
    }
    *(float4*)(Y + (size_t)(rowBase + ty * 2 + r) * U_ + colBase + tx * 4) = o;
  }
}

// ---------------------------------------------------------------------------
// Kernel 2: mu[b,j,i] = sum_u (A_ju + E_iu) * nu_u / (1 + A_ju * E_iu)
//   where A = tanh(att_de), E = tanh(att_en)   [tanh addition identity]
// then out[b,j,:] = softmax(mu + (mask-1)*1e6).
// grid = B * T_DE/2 blocks (512), 256 threads (4 waves).
// Wave w: i in [w*128, w*128+128), 4 i per iteration (isub = lane>>4).
// Lane covers u-span g*16..g*16+15 (g = lane&15), both j0 and j0+1.
// ---------------------------------------------------------------------------
__global__ __launch_bounds__(256) void attn_mu_softmax_kernel(
    const float* __restrict__ en_t, const float* __restrict__ de_t,
    const float* __restrict__ nu, const int* __restrict__ mask,
    float* __restrict__ out) {
  __shared__ float mu_s[2][T_EN_];

  const int tid  = threadIdx.x;
  const int lane = tid & 63;
  const int w    = tid >> 6;          // 0..3
  const int b    = blockIdx.x >> 6;   // / (T_DE/2)
  const int j0   = (blockIdx.x & 63) * 2;
  const int g    = lane & 15;         // u-group
  const int isub = lane >> 4;         // 0..3

  float A0[16], A1[16], nur[16], An0[16], An1[16];
  {
    const float* a0p = de_t + (size_t)(b * T_DE_ + j0) * U_ + g * 16;
    const float* nup = nu + g * 16;
    #pragma unroll
    for (int q = 0; q < 4; ++q) {
      const float4 v0 = *(const float4*)(a0p + 4 * q);
      const float4 v1 = *(const float4*)(a0p + U_ + 4 * q);
      const float4 nv = *(const float4*)(nup + 4 * q);
      A0[4 * q + 0] = v0.x; A0[4 * q + 1] = v0.y; A0[4 * q + 2] = v0.z; A0[4 * q + 3] = v0.w;
      A1[4 * q + 0] = v1.x; A1[4 * q + 1] = v1.y; A1[4 * q + 2] = v1.z; A1[4 * q + 3] = v1.w;
      nur[4 * q + 0] = nv.x; nur[4 * q + 1] = nv.y; nur[4 * q + 2] = nv.z; nur[4 * q + 3] = nv.w;
    }
    #pragma unroll
    for (int e = 0; e < 16; ++e) {
      An0[e] = A0[e] * nur[e];
      An1[e] = A1[e] * nur[e];
    }
  }

  const float* ebase = en_t + ((size_t)b * T_EN_ + w * 128 + isub) * U_ + g * 16;

  // software prefetch one 4-row step ahead
  float4 p0 = *(const float4*)(ebase + 0);
  float4 p1 = *(const float4*)(ebase + 4);
  float4 p2 = *(const float4*)(ebase + 8);
  float4 p3 = *(const float4*)(ebase + 12);

  for (int it = 0; it < 32; ++it) {
    const float4 E0 = p0, E1 = p1, E2 = p2, E3 = p3;
    if (it < 31) {
      const float* np = ebase + (size_t)(it + 1) * 4 * U_;
      p0 = *(const float4*)(np + 0);
      p1 = *(const float4*)(np + 4);
      p2 = *(const float4*)(np + 8);
      p3 = *(const float4*)(np + 12);
    }
    float E[16];
    E[0] = E0.x;  E[1] = E0.y;  E[2] = E0.z;  E[3] = E0.w;
    E[4] = E1.x;  E[5] = E1.y;  E[6] = E1.z;  E[7] = E1.w;
    E[8] = E2.x;  E[9] = E2.y;  E[10] = E2.z; E[11] = E2.w;
    E[12] = E3.x; E[13] = E3.y; E[14] = E3.z; E[15] = E3.w;

    float acc0 = 0.0f, acc1 = 0.0f;
    #pragma unroll
    for (int e = 0; e < 16; ++e) {
      const float num0 = fmaf(nur[e], E[e], An0[e]);
      const float den0 = fmaf(A0[e], E[e], 1.0f);
      acc0 = fmaf(num0, __builtin_amdgcn_rcpf(den0), acc0);
      const float num1 = fmaf(nur[e], E[e], An1[e]);
      const float den1 = fmaf(A1[e], E[e], 1.0f);
      acc1 = fmaf(num1, __builtin_amdgcn_rcpf(den1), acc1);
    }

    // reduce across the 16-lane u-group
    #pragma unroll
    for (int off = 1; off <= 8; off <<= 1) {
      acc0 += __shfl_xor(acc0, off, 64);
      acc1 += __shfl_xor(acc1, off, 64);
    }
    if (g == 0) {
      const int i = w * 128 + it * 4 + isub;
      mu_s[0][i] = acc0;
      mu_s[1][i] = acc1;
    }
  }

  __syncthreads();

  // Softmax: wave 0 -> j0, wave 1 -> j0+1
  if (w < 2) {
    const int jj = j0 + w;
    float vals[8];
    float mx = -3.0e38f;
    #pragma unroll
    for (int k = 0; k < 8; ++k) {
      const int i = lane + 64 * k;
      const float mi = (float)mask[b * T_EN_ + i];
      const float v = fmaf(mi - 1.0f, 1.0e6f, mu_s[w][i]);
      vals[k] = v;
      mx = fmaxf(mx, v);
    }
    #pragma unroll
    for (int off = 32; off; off >>= 1) mx = fmaxf(mx, __shfl_xor(mx, off, 64));
    float sum = 0.0f;
    #pragma unroll
    for (int k = 0; k < 8; ++k) {
      const float e = __builtin_amdgcn_exp2f((vals[k] - mx) * L2E_);
      vals[k] = e;
      sum += e;
    }
    #pragma unroll
    for (int off = 32; off; off >>= 1) sum += __shfl_xor(sum, off, 64);
    const float inv = __builtin_amdgcn_rcpf(sum);
    float* op = out + (size_t)(b * T_DE_ + jj) * T_EN_;
    #pragma unroll
    for (int k = 0; k < 8; ++k) op[lane + 64 * k] = vals[k] * inv;
  }
}

// ---------------------------------------------------------------------------
extern "C" void kernel_launch(void* const* d_in, const int* in_sizes, int n_in,
                              void* d_out, int out_size, void* d_ws, size_t ws_size,
                              hipStream_t stream) {
  const float* en   = (const float*)d_in[0];   // [B, T_EN, D]
  const float* de   = (const float*)d_in[1];   // [B, T_DE, D]
  const int*   mask = (const int*)d_in[2];     // [B, T_EN]
  const float* w_en = (const float*)d_in[3];   // [D, U]
  const float* w_de = (const float*)d_in[4];   // [D, U]
  const float* nu   = (const float*)d_in[5];   // [U, 1]
  float* out = (float*)d_out;                  // [B, T_DE, T_EN]

  float* en_t = (float*)d_ws;                          // tanh(en@w_en): 4 MB
  float* de_t = en_t + (size_t)B_ * T_EN_ * U_;        // tanh(de@w_de): 1 MB

  // Fused projections + tanh: 160 row-tiles (128 en + 32 de) x 8 col-tiles
  proj_tanh_kernel<<<dim3(160, 8), 128, 0, stream>>>(en, de, w_en, w_de, en_t, de_t);

  // tanh-addition-identity attention + masked softmax
  attn_mu_softmax_kernel<<<dim3(B_ * (T_DE_ / 2)), 256, 0, stream>>>(en_t, de_t, nu, mask, out);
}